// Round 3
// baseline (331.301 us; speedup 1.0000x reference)
//
#include <hip/hip_runtime.h>
#include <hip/hip_bf16.h>
#include <type_traits>

typedef __bf16 bf16x8 __attribute__((ext_vector_type(8)));
typedef float  f32x4  __attribute__((ext_vector_type(4)));

#define BDIM  2
#define HDIM  16
#define NDIM  2048
#define DDIM  64
#define BH    (BDIM*HDIM)
#define EPSF  1e-6f

#define QK_BLOCKS (BH * NDIM / 16)   // 4096
#define V_BLOCKS  (BH * NDIM / 64)   // 1024

__device__ __forceinline__ unsigned short f2bf(float x){
    union { float f; unsigned u; } a; a.f = x;
    unsigned r = a.u + 0x7fffu + ((a.u >> 16) & 1u);
    return (unsigned short)(r >> 16);
}

// ---------------------------------------------------------------------------
// prep: fused exp-map (q,k) + v transpose.
//   blocks [0, QK_BLOCKS):   16 rows/block, exp-map -> bf16 qh/kh + fp32 n2
//   blocks [QK_BLOCKS, ...): 64x64 tile transpose v -> bf16 vT [BH][D][N]
// ---------------------------------------------------------------------------
__global__ __launch_bounds__(256)
void prep(const float* __restrict__ q, const float* __restrict__ k,
          const float* __restrict__ v,
          unsigned short* __restrict__ qh, unsigned short* __restrict__ kh,
          unsigned short* __restrict__ vt,
          float* __restrict__ qn2, float* __restrict__ kn2,
          const float* __restrict__ cp)
{
    __shared__ float t[64][65];
    const int tid = threadIdx.x;

    if (blockIdx.x < QK_BLOCKS){
        const int row = blockIdx.x * 16 + (tid >> 4);
        const int c0  = (tid & 15) * 4;
        const float c   = fmaxf(cp[0], EPSF);
        const float sqc = sqrtf(c);

        // q row
        {
            float4 x = *(const float4*)(q + (size_t)row * DDIM + c0);
            float ss = fmaf(x.x, x.x, fmaf(x.y, x.y, fmaf(x.z, x.z, x.w * x.w)));
            #pragma unroll
            for (int off = 1; off < 16; off <<= 1) ss += __shfl_xor(ss, off);
            float sn    = fmaxf(sqrtf(ss), EPSF);
            float targ  = fminf(sqc * sn, 15.0f);
            float e     = exp2f(targ * 2.885390082f);      // exp(2*targ)
            float th    = (e - 1.0f) * __builtin_amdgcn_rcpf(e + 1.0f);
            float scale = th * __builtin_amdgcn_rcpf(sqc * sn);
            ushort4 o;
            o.x = f2bf(x.x * scale); o.y = f2bf(x.y * scale);
            o.z = f2bf(x.z * scale); o.w = f2bf(x.w * scale);
            *(ushort4*)(qh + (size_t)row * DDIM + c0) = o;
            if ((tid & 15) == 0) qn2[row] = ss * scale * scale;
        }
        // k row
        {
            float4 x = *(const float4*)(k + (size_t)row * DDIM + c0);
            float ss = fmaf(x.x, x.x, fmaf(x.y, x.y, fmaf(x.z, x.z, x.w * x.w)));
            #pragma unroll
            for (int off = 1; off < 16; off <<= 1) ss += __shfl_xor(ss, off);
            float sn    = fmaxf(sqrtf(ss), EPSF);
            float targ  = fminf(sqc * sn, 15.0f);
            float e     = exp2f(targ * 2.885390082f);
            float th    = (e - 1.0f) * __builtin_amdgcn_rcpf(e + 1.0f);
            float scale = th * __builtin_amdgcn_rcpf(sqc * sn);
            ushort4 o;
            o.x = f2bf(x.x * scale); o.y = f2bf(x.y * scale);
            o.z = f2bf(x.z * scale); o.w = f2bf(x.w * scale);
            *(ushort4*)(kh + (size_t)row * DDIM + c0) = o;
            if ((tid & 15) == 0) kn2[row] = ss * scale * scale;
        }
    } else {
        const int b  = blockIdx.x - QK_BLOCKS;
        const int bh = b >> 5;
        const int n0 = (b & 31) * 64;

        #pragma unroll
        for (int i = 0; i < 4; ++i){
            int ch  = tid + i * 256;
            int row = ch >> 4;
            int c4  = ch & 15;
            const float4 g = *(const float4*)(v + ((size_t)bh * NDIM + n0 + row) * DDIM + c4 * 4);
            t[row][c4*4 + 0] = g.x; t[row][c4*4 + 1] = g.y;
            t[row][c4*4 + 2] = g.z; t[row][c4*4 + 3] = g.w;
        }
        __syncthreads();
        #pragma unroll
        for (int i = 0; i < 4; ++i){
            int ch = tid + i * 256;
            int d  = ch >> 4;
            int nc = ch & 15;
            ushort4 o;
            o.x = f2bf(t[nc*4 + 0][d]); o.y = f2bf(t[nc*4 + 1][d]);
            o.z = f2bf(t[nc*4 + 2][d]); o.w = f2bf(t[nc*4 + 3][d]);
            *(ushort4*)(vt + ((size_t)bh * DDIM + d) * NDIM + n0 + nc * 4) = o;
        }
    }
}

// ---------------------------------------------------------------------------
// Barrier-free flash hyperbolic attention — ONE WAVE PER BLOCK.
// Grid (BH, 128): wave owns 16-row q-tile j = 127 - blockIdx.y (heavy first).
// K/V read directly from global (per-XCD L2-resident: bh fast grid dim).
// K fragments software-pipelined one tile ahead.
// ---------------------------------------------------------------------------
__global__ __launch_bounds__(64, 4)
void hyp_attn(const unsigned short* __restrict__ qh, const unsigned short* __restrict__ kh,
              const unsigned short* __restrict__ vtg,
              const float* __restrict__ qn2g, const float* __restrict__ kn2g,
              const float* __restrict__ cp, const float* __restrict__ bp,
              float* __restrict__ out)
{
    __shared__ unsigned short pw[16 * 72];

    const int bh  = blockIdx.x;
    const int j   = 127 - (int)blockIdx.y;      // q-tile; heavy tiles dispatch first
    const int l   = threadIdx.x & 63;
    const int l15 = l & 15;
    const int lg  = l >> 4;

    const float c   = fmaxf(cp[0], EPSF);
    const float sqc = sqrtf(c);
    const float nb2 = -bp[0] / sqc;             // log2-domain score scale
    const float tc  = 2.0f * c;

    const unsigned short* khb  = kh  + (size_t)bh * (NDIM * DDIM);
    const unsigned short* vtb  = vtg + (size_t)bh * (NDIM * DDIM);
    const float*          kn2b = kn2g + (size_t)bh * NDIM;

    // Q fragments (A layout: row = l15, k = 8*lg + jj)
    const int q0 = j * 16;
    const size_t qbase = ((size_t)bh * NDIM + (q0 + l15)) * DDIM;
    const bf16x8 qa0 = *(const bf16x8*)(qh + qbase + lg * 8);
    const bf16x8 qa1 = *(const bf16x8*)(qh + qbase + 32 + lg * 8);

    const int qr0 = q0 + lg * 4;                // acc-layout rows
    float qn2r[4], omq[4];
    #pragma unroll
    for (int r = 0; r < 4; ++r){
        qn2r[r] = qn2g[(size_t)bh * NDIM + qr0 + r];
        omq[r]  = 1.0f - c * qn2r[r];
    }

    float m2[4], lr[4];
    f32x4 O[4];
    #pragma unroll
    for (int r = 0; r < 4; ++r){ m2[r] = -1e30f; lr[r] = 0.0f; }
    #pragma unroll
    for (int vd = 0; vd < 4; ++vd) O[vd] = (f32x4){0.f, 0.f, 0.f, 0.f};

    const int ktend = j >> 2;

    // ---- prologue: prefetch K fragments + kn2 for kt = 0 ----
    bf16x8 kf0[4], kf1[4];
    float  kn2n[4];
    #pragma unroll
    for (int f = 0; f < 4; ++f){
        const unsigned short* kp = khb + (size_t)(f * 16 + l15) * DDIM + lg * 8;
        kf0[f] = *(const bf16x8*)(kp);
        kf1[f] = *(const bf16x8*)(kp + 32);
        kn2n[f] = kn2b[f * 16 + l15];
    }

    auto tile_body = [&](int kt, auto MASKC){
        constexpr bool MASK = decltype(MASKC)::value;
        const int k0 = kt * 64;

        // ---- S = Qh * Kh^T from prefetched fragments ----
        f32x4 S[4];
        #pragma unroll
        for (int f = 0; f < 4; ++f){
            f32x4 acc = (f32x4){0.f, 0.f, 0.f, 0.f};
            acc = __builtin_amdgcn_mfma_f32_16x16x32_bf16(qa0, kf0[f], acc, 0, 0, 0);
            acc = __builtin_amdgcn_mfma_f32_16x16x32_bf16(qa1, kf1[f], acc, 0, 0, 0);
            S[f] = acc;
        }
        float kn2m[4];
        #pragma unroll
        for (int f = 0; f < 4; ++f) kn2m[f] = kn2n[f];

        // ---- prefetch next K tile + kn2 (hidden under the transform) ----
        if (kt < ktend){
            const int k0n = k0 + 64;
            #pragma unroll
            for (int f = 0; f < 4; ++f){
                const unsigned short* kp = khb + (size_t)(k0n + f * 16 + l15) * DDIM + lg * 8;
                kf0[f] = *(const bf16x8*)(kp);
                kf1[f] = *(const bf16x8*)(kp + 32);
                kn2n[f] = kn2b[k0n + f * 16 + l15];
            }
        }
        // ---- V fragments for this tile ----
        bf16x8 vf[2][4];
        #pragma unroll
        for (int mc = 0; mc < 2; ++mc)
            #pragma unroll
            for (int vd = 0; vd < 4; ++vd)
                vf[mc][vd] = *(const bf16x8*)(vtb + (size_t)(vd * 16 + l15) * NDIM
                                              + k0 + mc * 32 + lg * 8);

        // ---- hyperbolic score transform (log2 domain) ----
        float sc[4][4], rmax[4];
        #pragma unroll
        for (int r = 0; r < 4; ++r) rmax[r] = -1e30f;
        #pragma unroll
        for (int f = 0; f < 4; ++f){
            const float kn2v = kn2m[f];
            const float omk  = 1.0f - c * kn2v;
            #pragma unroll
            for (int r = 0; r < 4; ++r){
                float diff = fmaf(-2.0f, S[f][r], qn2r[r] + kn2v);
                float den  = fmaxf(omq[r] * omk, EPSF);
                float arg  = fmaxf(fmaf(tc * diff, __builtin_amdgcn_rcpf(den), 1.0f), 1.0f + EPSF);
                float w    = arg + sqrtf(fmaf(arg, arg, -1.0f));
                float s2   = nb2 * __log2f(w);
                if (MASK) s2 = (k0 + f * 16 + l15 > qr0 + r) ? -1e30f : s2;
                sc[f][r] = s2;
                rmax[r]  = fmaxf(rmax[r], s2);
            }
        }
        #pragma unroll
        for (int r = 0; r < 4; ++r){
            #pragma unroll
            for (int off = 1; off < 16; off <<= 1)
                rmax[r] = fmaxf(rmax[r], __shfl_xor(rmax[r], off));
        }
        bool up = (rmax[0] > m2[0]) | (rmax[1] > m2[1]) |
                  (rmax[2] > m2[2]) | (rmax[3] > m2[3]);
        if (__any(up)){
            #pragma unroll
            for (int r = 0; r < 4; ++r){
                float nm  = fmaxf(m2[r], rmax[r]);
                float scl = exp2f(m2[r] - nm);
                lr[r] *= scl; m2[r] = nm;
                #pragma unroll
                for (int vd = 0; vd < 4; ++vd) O[vd][r] *= scl;
            }
        }

        // ---- P = exp2(s' - m'), row sums, swizzled store to wave-private LDS ----
        float psum[4] = {0.f, 0.f, 0.f, 0.f};
        #pragma unroll
        for (int f = 0; f < 4; ++f){
            const int fx = ((f ^ lg) << 4) + l15;
            #pragma unroll
            for (int r = 0; r < 4; ++r){
                float p = exp2f(sc[f][r] - m2[r]);
                psum[r] += p;
                pw[(lg * 4 + r) * 72 + fx] = f2bf(p);
            }
        }
        #pragma unroll
        for (int r = 0; r < 4; ++r){
            #pragma unroll
            for (int off = 1; off < 16; off <<= 1)
                psum[r] += __shfl_xor(psum[r], off);
            lr[r] += psum[r];
        }

        asm volatile("s_waitcnt lgkmcnt(0)" ::: "memory");

        // ---- O += P * V ----
        #pragma unroll
        for (int mc = 0; mc < 2; ++mc){
            const int f  = 2 * mc + (lg >> 1);
            const int fx = f ^ ((l15 >> 2) & 3);
            bf16x8 pa = *(const bf16x8*)&pw[l15 * 72 + fx * 16 + (lg & 1) * 8];
            #pragma unroll
            for (int vd = 0; vd < 4; ++vd)
                O[vd] = __builtin_amdgcn_mfma_f32_16x16x32_bf16(pa, vf[mc][vd], O[vd], 0, 0, 0);
        }
    };

    for (int kt = 0; kt < ktend; ++kt) tile_body(kt, std::bool_constant<false>{});
    tile_body(ktend, std::bool_constant<true>{});

    // ---- epilogue ----
    #pragma unroll
    for (int r = 0; r < 4; ++r){
        float rl = __builtin_amdgcn_rcpf(lr[r]);
        #pragma unroll
        for (int vd = 0; vd < 4; ++vd)
            out[((size_t)bh * NDIM + qr0 + r) * DDIM + vd * 16 + l15] = O[vd][r] * rl;
    }
}

// ---------------------------------------------------------------------------
extern "C" void kernel_launch(void* const* d_in, const int* in_sizes, int n_in,
                              void* d_out, int out_size, void* d_ws, size_t ws_size,
                              hipStream_t stream)
{
    const float* q   = (const float*)d_in[0];
    const float* k   = (const float*)d_in[1];
    const float* v   = (const float*)d_in[2];
    const float* cp  = (const float*)d_in[3];
    const float* bp  = (const float*)d_in[4];
    float*       out = (float*)d_out;

    char* ws = (char*)d_ws;
    const size_t elems = (size_t)BH * NDIM * DDIM;
    unsigned short* qh  = (unsigned short*)ws;  ws += elems * 2;
    unsigned short* kh  = (unsigned short*)ws;  ws += elems * 2;
    unsigned short* vt  = (unsigned short*)ws;  ws += elems * 2;
    float*          qn2 = (float*)ws;           ws += (size_t)BH * NDIM * 4;
    float*          kn2 = (float*)ws;

    prep<<<QK_BLOCKS + V_BLOCKS, 256, 0, stream>>>(q, k, v, qh, kh, vt, qn2, kn2, cp);
    hyp_attn<<<dim3(BH, 128), 64, 0, stream>>>(qh, kh, vt, qn2, kn2, cp, bp, out);
}

// Round 4
// 236.771 us; speedup vs baseline: 1.3992x; 1.3992x over previous
//
#include <hip/hip_runtime.h>
#include <hip/hip_bf16.h>

typedef __bf16 bf16x8 __attribute__((ext_vector_type(8)));
typedef float  f32x4  __attribute__((ext_vector_type(4)));

#define BDIM  2
#define HDIM  16
#define NDIM  2048
#define DDIM  64
#define BH    (BDIM*HDIM)
#define EPSF  1e-6f

#define QK_BLOCKS (BH * NDIM / 16)   // 4096
#define V_BLOCKS  (BH * NDIM / 64)   // 1024

__device__ __forceinline__ unsigned short f2bf(float x){
    union { float f; unsigned u; } a; a.f = x;
    unsigned r = a.u + 0x7fffu + ((a.u >> 16) & 1u);
    return (unsigned short)(r >> 16);
}

// ---------------------------------------------------------------------------
// prep: fused exp-map (q,k) + v transpose.
//   blocks [0, QK_BLOCKS):   16 rows/block, exp-map -> bf16 qh/kh + fp32 n2
//   blocks [QK_BLOCKS, ...): 64x64 tile transpose v -> bf16 vT [BH][D][N]
// ---------------------------------------------------------------------------
__global__ __launch_bounds__(256)
void prep(const float* __restrict__ q, const float* __restrict__ k,
          const float* __restrict__ v,
          unsigned short* __restrict__ qh, unsigned short* __restrict__ kh,
          unsigned short* __restrict__ vt,
          float* __restrict__ qn2, float* __restrict__ kn2,
          const float* __restrict__ cp)
{
    __shared__ float t[64][65];
    const int tid = threadIdx.x;

    if (blockIdx.x < QK_BLOCKS){
        const int row = blockIdx.x * 16 + (tid >> 4);
        const int c0  = (tid & 15) * 4;
        const float c   = fmaxf(cp[0], EPSF);
        const float sqc = sqrtf(c);

        // q row
        {
            float4 x = *(const float4*)(q + (size_t)row * DDIM + c0);
            float ss = fmaf(x.x, x.x, fmaf(x.y, x.y, fmaf(x.z, x.z, x.w * x.w)));
            #pragma unroll
            for (int off = 1; off < 16; off <<= 1) ss += __shfl_xor(ss, off);
            float sn    = fmaxf(sqrtf(ss), EPSF);
            float targ  = fminf(sqc * sn, 15.0f);
            float e     = exp2f(targ * 2.885390082f);      // exp(2*targ)
            float th    = (e - 1.0f) * __builtin_amdgcn_rcpf(e + 1.0f);
            float scale = th * __builtin_amdgcn_rcpf(sqc * sn);
            ushort4 o;
            o.x = f2bf(x.x * scale); o.y = f2bf(x.y * scale);
            o.z = f2bf(x.z * scale); o.w = f2bf(x.w * scale);
            *(ushort4*)(qh + (size_t)row * DDIM + c0) = o;
            if ((tid & 15) == 0) qn2[row] = ss * scale * scale;
        }
        // k row
        {
            float4 x = *(const float4*)(k + (size_t)row * DDIM + c0);
            float ss = fmaf(x.x, x.x, fmaf(x.y, x.y, fmaf(x.z, x.z, x.w * x.w)));
            #pragma unroll
            for (int off = 1; off < 16; off <<= 1) ss += __shfl_xor(ss, off);
            float sn    = fmaxf(sqrtf(ss), EPSF);
            float targ  = fminf(sqc * sn, 15.0f);
            float e     = exp2f(targ * 2.885390082f);
            float th    = (e - 1.0f) * __builtin_amdgcn_rcpf(e + 1.0f);
            float scale = th * __builtin_amdgcn_rcpf(sqc * sn);
            ushort4 o;
            o.x = f2bf(x.x * scale); o.y = f2bf(x.y * scale);
            o.z = f2bf(x.z * scale); o.w = f2bf(x.w * scale);
            *(ushort4*)(kh + (size_t)row * DDIM + c0) = o;
            if ((tid & 15) == 0) kn2[row] = ss * scale * scale;
        }
    } else {
        const int b  = blockIdx.x - QK_BLOCKS;
        const int bh = b >> 5;
        const int n0 = (b & 31) * 64;

        #pragma unroll
        for (int i = 0; i < 4; ++i){
            int ch  = tid + i * 256;
            int row = ch >> 4;
            int c4  = ch & 15;
            const float4 g = *(const float4*)(v + ((size_t)bh * NDIM + n0 + row) * DDIM + c4 * 4);
            t[row][c4*4 + 0] = g.x; t[row][c4*4 + 1] = g.y;
            t[row][c4*4 + 2] = g.z; t[row][c4*4 + 3] = g.w;
        }
        __syncthreads();
        #pragma unroll
        for (int i = 0; i < 4; ++i){
            int ch = tid + i * 256;
            int d  = ch >> 4;
            int nc = ch & 15;
            ushort4 o;
            o.x = f2bf(t[nc*4 + 0][d]); o.y = f2bf(t[nc*4 + 1][d]);
            o.z = f2bf(t[nc*4 + 2][d]); o.w = f2bf(t[nc*4 + 3][d]);
            *(ushort4*)(vt + ((size_t)bh * DDIM + d) * NDIM + n0 + nc * 4) = o;
        }
    }
}

// ---------------------------------------------------------------------------
// Barrier-free flash hyperbolic attention — ONE WAVE PER BLOCK, fully inline.
// Grid (BH, 128): wave owns q-tile j = 127 - blockIdx.y (heavy first).
// K/V read directly from global (per-XCD L2-resident: bh is fast grid dim).
// ---------------------------------------------------------------------------
__global__ __launch_bounds__(64, 4)
void hyp_attn(const unsigned short* __restrict__ qh, const unsigned short* __restrict__ kh,
              const unsigned short* __restrict__ vtg,
              const float* __restrict__ qn2g, const float* __restrict__ kn2g,
              const float* __restrict__ cp, const float* __restrict__ bp,
              float* __restrict__ out)
{
    __shared__ unsigned short pw[16 * 72];

    const int bh  = blockIdx.x;
    const int j   = 127 - (int)blockIdx.y;      // heavy tiles dispatch first
    const int l   = threadIdx.x & 63;
    const int l15 = l & 15;
    const int lg  = l >> 4;

    const float c   = fmaxf(cp[0], EPSF);
    const float sqc = sqrtf(c);
    const float nb2 = -bp[0] / sqc;             // log2-domain score scale
    const float tc  = 2.0f * c;

    const unsigned short* khb  = kh  + (size_t)bh * (NDIM * DDIM);
    const unsigned short* vtb  = vtg + (size_t)bh * (NDIM * DDIM);
    const float*          kn2b = kn2g + (size_t)bh * NDIM;

    // Q fragments (A layout: row = l15, k = 8*lg + jj)
    const int q0 = j * 16;
    const size_t qbase = ((size_t)bh * NDIM + (q0 + l15)) * DDIM;
    const bf16x8 qa0 = *(const bf16x8*)(qh + qbase + lg * 8);
    const bf16x8 qa1 = *(const bf16x8*)(qh + qbase + 32 + lg * 8);

    const int qr0 = q0 + lg * 4;                // acc-layout rows
    float qn2r[4], omq[4];
    #pragma unroll
    for (int r = 0; r < 4; ++r){
        qn2r[r] = qn2g[(size_t)bh * NDIM + qr0 + r];
        omq[r]  = 1.0f - c * qn2r[r];
    }

    float m2[4], lr[4];
    f32x4 O[4];
    #pragma unroll
    for (int r = 0; r < 4; ++r){ m2[r] = -1e30f; lr[r] = 0.0f; }
    #pragma unroll
    for (int vd = 0; vd < 4; ++vd) O[vd] = (f32x4){0.f, 0.f, 0.f, 0.f};

    const int ktend = j >> 2;

    for (int kt = 0; kt <= ktend; ++kt){
        const int k0 = kt * 64;

        // ---- K fragments + kn2 ----
        bf16x8 kf0[4], kf1[4];
        float  kn2m[4];
        #pragma unroll
        for (int f = 0; f < 4; ++f){
            const unsigned short* kp = khb + (size_t)(k0 + f * 16 + l15) * DDIM + lg * 8;
            kf0[f]  = *(const bf16x8*)(kp);
            kf1[f]  = *(const bf16x8*)(kp + 32);
            kn2m[f] = kn2b[k0 + f * 16 + l15];
        }

        // ---- S = Qh * Kh^T ----
        f32x4 S[4];
        #pragma unroll
        for (int f = 0; f < 4; ++f){
            f32x4 acc = (f32x4){0.f, 0.f, 0.f, 0.f};
            acc = __builtin_amdgcn_mfma_f32_16x16x32_bf16(qa0, kf0[f], acc, 0, 0, 0);
            acc = __builtin_amdgcn_mfma_f32_16x16x32_bf16(qa1, kf1[f], acc, 0, 0, 0);
            S[f] = acc;
        }

        // ---- V fragments (issue early; latency hides under the transform) ----
        bf16x8 vf[2][4];
        #pragma unroll
        for (int mc = 0; mc < 2; ++mc)
            #pragma unroll
            for (int vd = 0; vd < 4; ++vd)
                vf[mc][vd] = *(const bf16x8*)(vtb + (size_t)(vd * 16 + l15) * NDIM
                                              + k0 + mc * 32 + lg * 8);

        // ---- hyperbolic score transform (log2 domain), in place over S ----
        #pragma unroll
        for (int f = 0; f < 4; ++f){
            const float kn2v = kn2m[f];
            const float omk  = 1.0f - c * kn2v;
            #pragma unroll
            for (int r = 0; r < 4; ++r){
                float diff = fmaf(-2.0f, S[f][r], qn2r[r] + kn2v);
                float den  = fmaxf(omq[r] * omk, EPSF);
                float arg  = fmaxf(fmaf(tc * diff, __builtin_amdgcn_rcpf(den), 1.0f), 1.0f + EPSF);
                float w    = arg + sqrtf(fmaf(arg, arg, -1.0f));
                S[f][r]    = nb2 * __log2f(w);
            }
        }
        // ---- causal mask fixup (diagonal tile only; wave-uniform branch) ----
        if (kt == ktend){
            #pragma unroll
            for (int f = 0; f < 4; ++f){
                const int m = k0 + f * 16 + l15;
                #pragma unroll
                for (int r = 0; r < 4; ++r)
                    if (m > qr0 + r) S[f][r] = -1e30f;
            }
        }

        // ---- row max across 16 lanes of each row group ----
        float rmax[4];
        #pragma unroll
        for (int r = 0; r < 4; ++r){
            rmax[r] = fmaxf(fmaxf(S[0][r], S[1][r]), fmaxf(S[2][r], S[3][r]));
            #pragma unroll
            for (int off = 1; off < 16; off <<= 1)
                rmax[r] = fmaxf(rmax[r], __shfl_xor(rmax[r], off));
        }
        bool up = (rmax[0] > m2[0]) | (rmax[1] > m2[1]) |
                  (rmax[2] > m2[2]) | (rmax[3] > m2[3]);
        if (__any(up)){
            #pragma unroll
            for (int r = 0; r < 4; ++r){
                float nm  = fmaxf(m2[r], rmax[r]);
                float scl = exp2f(m2[r] - nm);
                lr[r] *= scl; m2[r] = nm;
                #pragma unroll
                for (int vd = 0; vd < 4; ++vd) O[vd][r] *= scl;
            }
        }

        // ---- P = exp2(s' - m'), row sums, swizzled store to LDS ----
        float psum[4] = {0.f, 0.f, 0.f, 0.f};
        #pragma unroll
        for (int f = 0; f < 4; ++f){
            const int fx = ((f ^ lg) << 4) + l15;
            #pragma unroll
            for (int r = 0; r < 4; ++r){
                float p = exp2f(S[f][r] - m2[r]);
                psum[r] += p;
                pw[(lg * 4 + r) * 72 + fx] = f2bf(p);
            }
        }
        #pragma unroll
        for (int r = 0; r < 4; ++r){
            #pragma unroll
            for (int off = 1; off < 16; off <<= 1)
                psum[r] += __shfl_xor(psum[r], off);
            lr[r] += psum[r];
        }

        asm volatile("s_waitcnt lgkmcnt(0)" ::: "memory");   // wave-private LDS

        // ---- O += P * V ----
        #pragma unroll
        for (int mc = 0; mc < 2; ++mc){
            const int f  = 2 * mc + (lg >> 1);
            const int fx = f ^ ((l15 >> 2) & 3);
            bf16x8 pa = *(const bf16x8*)&pw[l15 * 72 + fx * 16 + (lg & 1) * 8];
            #pragma unroll
            for (int vd = 0; vd < 4; ++vd)
                O[vd] = __builtin_amdgcn_mfma_f32_16x16x32_bf16(pa, vf[mc][vd], O[vd], 0, 0, 0);
        }
    }

    // ---- epilogue ----
    #pragma unroll
    for (int r = 0; r < 4; ++r){
        float rl = __builtin_amdgcn_rcpf(lr[r]);
        #pragma unroll
        for (int vd = 0; vd < 4; ++vd)
            out[((size_t)bh * NDIM + qr0 + r) * DDIM + vd * 16 + l15] = O[vd][r] * rl;
    }
}

// ---------------------------------------------------------------------------
extern "C" void kernel_launch(void* const* d_in, const int* in_sizes, int n_in,
                              void* d_out, int out_size, void* d_ws, size_t ws_size,
                              hipStream_t stream)
{
    const float* q   = (const float*)d_in[0];
    const float* k   = (const float*)d_in[1];
    const float* v   = (const float*)d_in[2];
    const float* cp  = (const float*)d_in[3];
    const float* bp  = (const float*)d_in[4];
    float*       out = (float*)d_out;

    char* ws = (char*)d_ws;
    const size_t elems = (size_t)BH * NDIM * DDIM;
    unsigned short* qh  = (unsigned short*)ws;  ws += elems * 2;
    unsigned short* kh  = (unsigned short*)ws;  ws += elems * 2;
    unsigned short* vt  = (unsigned short*)ws;  ws += elems * 2;
    float*          qn2 = (float*)ws;           ws += (size_t)BH * NDIM * 4;
    float*          kn2 = (float*)ws;

    prep<<<QK_BLOCKS + V_BLOCKS, 256, 0, stream>>>(q, k, v, qh, kh, vt, qn2, kn2, cp);
    hyp_attn<<<dim3(BH, 128), 64, 0, stream>>>(qh, kh, vt, qn2, kn2, cp, bp, out);
}